// Round 14
// baseline (109.375 us; speedup 1.0000x reference)
//
#include <hip/hip_runtime.h>
#include <hip/hip_bf16.h>

#define FEAT 128
#define BINW 128            // nodes per coarse bin (power of 2)
#define BINSHIFT 7
#define MAXBIN 1024
#define CAP 4096            // fixed pair-region capacity per bin (45 sigma)
#define TB 8192             // edges per edge-block
#define BBS 1024            // build kernel block size

__device__ __forceinline__ unsigned short f2b(float f) {
    __hip_bfloat16 h = __float2bfloat16(f);   // RNE
    return *reinterpret_cast<unsigned short*>(&h);
}
__device__ __forceinline__ float b2f_lo(unsigned u) {   // low ushort -> f32
    unsigned x = u << 16;
    float f;
    __builtin_memcpy(&f, &x, 4);
    return f;
}
__device__ __forceinline__ float b2f_hi(unsigned u) {   // high ushort -> f32
    unsigned x = u & 0xFFFF0000u;
    float f;
    __builtin_memcpy(&f, &x, 4);
    return f;
}
__device__ __forceinline__ unsigned int pack2(float lo, float hi) {
    return (unsigned int)f2b(lo) | ((unsigned int)f2b(hi) << 16);
}

// ===========================================================================
// MAIN PATH (memset + 3 kernels):
//  K1 role-split build: edge blocks (hist+alloc+scatter, dst staged in LDS)
//                       || convert blocks (bf16 feat stream)
//  K2 per-bin fine sort (1024t) -> nodeinfo{off,deg}
//  K3 per-node register gather
// ===========================================================================

// K1: blocks [0,NTILE) = edge blocks: load dst once (staged to LDS), LDS-hist,
// reserve per-bin chunks via one returning atomicAdd(binCursor[b], h[b]),
// scatter packed (src | local_dst<<17) into pair[b*CAP + chunk ..).
// Blocks [NTILE, NTILE+GC) = convert blocks: feat16 = bf16(weight*cj).
__global__ void __launch_bounds__(BBS)
build_kernel(const float* __restrict__ weight,
             const float* __restrict__ cj,
             const int* __restrict__ src,
             const int* __restrict__ dst,
             unsigned short* __restrict__ feat16,
             unsigned* __restrict__ pair,
             int* __restrict__ binCursor,
             int N, int E, int NBIN, int NTILE, int ipt) {
    __shared__ int h[MAXBIN];
    __shared__ int base_l[MAXBIN];
    __shared__ int dstS[TB];
    int tile = blockIdx.x;
    int t = threadIdx.x;

    if (tile >= NTILE) {
        // ---- convert block ----
        int NC = N * (FEAT / 8);
        int cb = tile - NTILE;
        int cbase = cb * BBS * ipt;
        for (int j = 0; j < ipt; ++j) {
            int i = cbase + j * BBS + t;
            if (i < NC) {
                int row = i >> 4;
                int seg = i & 15;
                float c = cj[row];
                const float4* p = reinterpret_cast<const float4*>(
                    weight + (size_t)row * FEAT + seg * 8);
                float4 a = p[0], b4 = p[1];
                uint4 o;
                o.x = pack2(a.x * c, a.y * c);
                o.y = pack2(a.z * c, a.w * c);
                o.z = pack2(b4.x * c, b4.y * c);
                o.w = pack2(b4.z * c, b4.w * c);
                *reinterpret_cast<uint4*>(feat16 + (size_t)i * 8) = o;
            }
        }
        return;
    }

    // ---- edge block ----
    for (int b = t; b < NBIN; b += BBS) h[b] = 0;
    __syncthreads();
    int e0 = tile * TB;
    #pragma unroll
    for (int i = 0; i < TB / BBS; ++i) {
        int e = e0 + i * BBS + t;
        int d = (e < E) ? dst[e] : -1;
        dstS[i * BBS + t] = d;
        if (d >= 0) atomicAdd(&h[d >> BINSHIFT], 1);
    }
    __syncthreads();
    // reserve contiguous chunk per (tile, bin); reset h to serve as cursor
    for (int b = t; b < NBIN; b += BBS) {
        int c = h[b];
        int a = (c > 0) ? atomicAdd(&binCursor[b], c) : 0;
        base_l[b] = b * CAP + a;
        h[b] = 0;
    }
    __syncthreads();
    #pragma unroll
    for (int i = 0; i < TB / BBS; ++i) {
        int e = e0 + i * BBS + t;
        if (e < E) {
            int d = dstS[i * BBS + t];
            int b = d >> BINSHIFT;
            int pos = atomicAdd(&h[b], 1);
            int idx = base_l[b] + pos;
            if (idx < (b + 1) * CAP)         // clamp (never fires at ~45-sigma CAP)
                pair[idx] = (unsigned)src[e] | ((unsigned)(d & (BINW - 1)) << 17);
        }
    }
}

// K2: per-bin fine counting sort, 1024 threads/block. Stages the segment in
// LDS (len <= CAP by construction), 128-counter hist + scan, rewrites `pair`
// grouped by node, emits nodeinfo[node] = {absolute off, deg}. LDS atomics.
__global__ void __launch_bounds__(1024)
fine_sort_kernel(unsigned* __restrict__ pair,
                 const int* __restrict__ binCursor,
                 int2* __restrict__ nodeinfo,
                 int N) {
    __shared__ int cnt[BINW];
    __shared__ int sbase[BINW];
    __shared__ unsigned stage[CAP];
    int bin = blockIdx.x;
    int t = threadIdx.x;
    if (t < BINW) cnt[t] = 0;
    __syncthreads();
    int start = bin * CAP;
    int len = binCursor[bin];
    if (len > CAP) len = CAP;

    for (int k = t; k < len; k += 1024) {
        unsigned p = pair[start + k];
        stage[k] = p;
        atomicAdd(&cnt[p >> 17], 1);
    }
    __syncthreads();
    int mine = (t < BINW) ? cnt[t] : 0;
    if (t < BINW) sbase[t] = mine;
    __syncthreads();
    for (int d = 1; d < BINW; d <<= 1) {     // Hillis-Steele inclusive scan
        int v = 0;
        if (t < BINW && t >= d) v = sbase[t - d];
        __syncthreads();
        if (t < BINW) sbase[t] += v;
        __syncthreads();
    }
    if (t < BINW) {
        int excl = sbase[t] - mine;
        int node = (bin << BINSHIFT) + t;
        if (node < N) nodeinfo[node] = make_int2(start + excl, mine);
        sbase[t] = start + excl;             // absolute base per local node
        cnt[t] = 0;                          // reuse as cursor
    }
    __syncthreads();
    for (int k = t; k < len; k += 1024) {
        unsigned p = stage[k];
        int ld = p >> 17;
        int pos = atomicAdd(&cnt[ld], 1);
        pair[sbase[ld] + pos] = p & 0x1FFFF;
    }
}

// K3: one 64-lane wave per node, 4x16-lane quarters; 16 B (8 bf16 feats)
// per lane per edge, unroll 4; two shfl_xor levels; quarter 0 writes 32 B.
__global__ void gather_kernel(const unsigned short* __restrict__ feat16,
                              const float* __restrict__ ci,
                              const int2* __restrict__ nodeinfo,
                              const int* __restrict__ src_sorted,
                              float* __restrict__ out, int N) {
    int gt = blockIdx.x * blockDim.x + threadIdx.x;
    int node = gt >> 6;
    if (node >= N) return;
    int lane = gt & 63;
    int fi   = (lane & 15) << 3;         // feature offset (0,8,...,120)
    int q    = lane >> 4;                // quarter 0..3
    int2 ni  = nodeinfo[node];
    int start = ni.x;
    int end   = ni.x + ni.y;
    float acc[8] = {0.f, 0.f, 0.f, 0.f, 0.f, 0.f, 0.f, 0.f};
    #pragma unroll 4
    for (int k = start + q; k < end; k += 4) {
        int s = src_sorted[k];
        uint4 u = *reinterpret_cast<const uint4*>(feat16 + ((size_t)s << 7) + fi);
        acc[0] += b2f_lo(u.x); acc[1] += b2f_hi(u.x);
        acc[2] += b2f_lo(u.y); acc[3] += b2f_hi(u.y);
        acc[4] += b2f_lo(u.z); acc[5] += b2f_hi(u.z);
        acc[6] += b2f_lo(u.w); acc[7] += b2f_hi(u.w);
    }
    #pragma unroll
    for (int j = 0; j < 8; ++j) {
        acc[j] += __shfl_xor(acc[j], 16);
        acc[j] += __shfl_xor(acc[j], 32);
    }
    if (q == 0) {
        float c = ci[node];
        float4 v0 = make_float4(acc[0] * c, acc[1] * c, acc[2] * c, acc[3] * c);
        float4 v1 = make_float4(acc[4] * c, acc[5] * c, acc[6] * c, acc[7] * c);
        float* o = out + ((size_t)node << 7) + fi;
        *reinterpret_cast<float4*>(o)     = v0;
        *reinterpret_cast<float4*>(o + 4) = v1;
    }
}

// ===========================================================================
// MID TIER (verified): per-node CSR + bf16 gather
// ===========================================================================

__global__ void zero_ints_kernel(int* __restrict__ p, int n) {
    int i = blockIdx.x * blockDim.x + threadIdx.x;
    if (i < n) p[i] = 0;
}

__global__ void convert_hist_kernel(const float* __restrict__ weight,
                                    const float* __restrict__ cj,
                                    const int* __restrict__ dst,
                                    int* __restrict__ counts,
                                    unsigned short* __restrict__ feat16,
                                    int N, int E) {
    int i = blockIdx.x * blockDim.x + threadIdx.x;
    int NC = N * (FEAT / 8);
    if (i < NC) {
        int row = i >> 4;
        int seg = i & 15;
        float c = cj[row];
        const float4* p = reinterpret_cast<const float4*>(weight + (size_t)row * FEAT + seg * 8);
        float4 a = p[0], b = p[1];
        uint4 o;
        o.x = pack2(a.x * c, a.y * c);
        o.y = pack2(a.z * c, a.w * c);
        o.z = pack2(b.x * c, b.y * c);
        o.w = pack2(b.z * c, b.w * c);
        *reinterpret_cast<uint4*>(feat16 + (size_t)i * 8) = o;
    }
    if (i < E) atomicAdd(&counts[dst[i]], 1);
}

__global__ void block_sum_kernel(const int* __restrict__ counts, int* __restrict__ bsum, int N) {
    __shared__ int s[256];
    int i = blockIdx.x * 256 + threadIdx.x;
    s[threadIdx.x] = (i < N) ? counts[i] : 0;
    __syncthreads();
    for (int off = 128; off > 0; off >>= 1) {
        if (threadIdx.x < off) s[threadIdx.x] += s[threadIdx.x + off];
        __syncthreads();
    }
    if (threadIdx.x == 0) bsum[blockIdx.x] = s[0];
}

__global__ void scan_bsum_kernel(int* __restrict__ bsum, int nb) {
    __shared__ int s[512];
    int t = threadIdx.x;
    int mine = (t < nb) ? bsum[t] : 0;
    s[t] = mine;
    __syncthreads();
    for (int off = 1; off < 512; off <<= 1) {
        int v = (t >= off) ? s[t - off] : 0;
        __syncthreads();
        s[t] += v;
        __syncthreads();
    }
    if (t < nb) bsum[t] = s[t] - mine;
}

__global__ void scan_counts_kernel(const int* __restrict__ counts, const int* __restrict__ bsum,
                                   int* __restrict__ offsets, int* __restrict__ cursor,
                                   int N, int E) {
    __shared__ int s[256];
    int t = threadIdx.x;
    int i = blockIdx.x * 256 + t;
    int mine = (i < N) ? counts[i] : 0;
    s[t] = mine;
    __syncthreads();
    for (int off = 1; off < 256; off <<= 1) {
        int v = (t >= off) ? s[t - off] : 0;
        __syncthreads();
        s[t] += v;
        __syncthreads();
    }
    if (i < N) {
        int o = bsum[blockIdx.x] + s[t] - mine;
        offsets[i] = o;
        cursor[i] = o;
    }
    if (i == 0 && blockIdx.x == 0) offsets[N] = E;
}

__global__ void bucket_kernel(const int* __restrict__ src, const int* __restrict__ dst,
                              int* __restrict__ cursor,
                              int* __restrict__ src_sorted, int E) {
    int i = blockIdx.x * blockDim.x + threadIdx.x;
    if (i < E) {
        int pos = atomicAdd(&cursor[dst[i]], 1);
        src_sorted[pos] = src[i];
    }
}

__global__ void gather_mid_kernel(const unsigned short* __restrict__ feat16,
                                  const float* __restrict__ ci,
                                  const int* __restrict__ offsets,
                                  const int* __restrict__ src_sorted,
                                  float* __restrict__ out, int N) {
    int gt = blockIdx.x * blockDim.x + threadIdx.x;
    int node = gt >> 6;
    if (node >= N) return;
    int lane = gt & 63;
    int fi   = (lane & 15) << 3;
    int q    = lane >> 4;
    int start = offsets[node];
    int end   = offsets[node + 1];
    float acc[8] = {0.f, 0.f, 0.f, 0.f, 0.f, 0.f, 0.f, 0.f};
    #pragma unroll 4
    for (int k = start + q; k < end; k += 4) {
        int s = src_sorted[k];
        uint4 u = *reinterpret_cast<const uint4*>(feat16 + ((size_t)s << 7) + fi);
        acc[0] += b2f_lo(u.x); acc[1] += b2f_hi(u.x);
        acc[2] += b2f_lo(u.y); acc[3] += b2f_hi(u.y);
        acc[4] += b2f_lo(u.z); acc[5] += b2f_hi(u.z);
        acc[6] += b2f_lo(u.w); acc[7] += b2f_hi(u.w);
    }
    #pragma unroll
    for (int j = 0; j < 8; ++j) {
        acc[j] += __shfl_xor(acc[j], 16);
        acc[j] += __shfl_xor(acc[j], 32);
    }
    if (q == 0) {
        float c = ci[node];
        float4 v0 = make_float4(acc[0] * c, acc[1] * c, acc[2] * c, acc[3] * c);
        float4 v1 = make_float4(acc[4] * c, acc[5] * c, acc[6] * c, acc[7] * c);
        float* o = out + ((size_t)node << 7) + fi;
        *reinterpret_cast<float4*>(o)     = v0;
        *reinterpret_cast<float4*>(o + 4) = v1;
    }
}

// ===========================================================================
// LAST TIER (round-1 verified): float atomics
// ===========================================================================

__global__ void gcmc_zero_kernel(float4* __restrict__ out, int n4) {
    int i = blockIdx.x * blockDim.x + threadIdx.x;
    if (i < n4) out[i] = make_float4(0.f, 0.f, 0.f, 0.f);
}

__global__ void gcmc_scatter_kernel(const float* __restrict__ weight,
                                    const float* __restrict__ cj,
                                    const int* __restrict__ src,
                                    const int* __restrict__ dst,
                                    float* __restrict__ out,
                                    int n_edges) {
    int t = blockIdx.x * blockDim.x + threadIdx.x;
    int e = t >> 5;
    int f = (t & 31) << 2;
    if (e >= n_edges) return;
    int s = src[e];
    int d = dst[e];
    float c = cj[s];
    const float4 w = *reinterpret_cast<const float4*>(weight + (size_t)s * FEAT + f);
    float* o = out + (size_t)d * FEAT + f;
    unsafeAtomicAdd(o + 0, w.x * c);
    unsafeAtomicAdd(o + 1, w.y * c);
    unsafeAtomicAdd(o + 2, w.z * c);
    unsafeAtomicAdd(o + 3, w.w * c);
}

__global__ void gcmc_scale_kernel(float4* __restrict__ out,
                                  const float* __restrict__ ci, int n4) {
    int i = blockIdx.x * blockDim.x + threadIdx.x;
    if (i < n4) {
        float c = ci[i >> 5];
        float4 v = out[i];
        v.x *= c; v.y *= c; v.z *= c; v.w *= c;
        out[i] = v;
    }
}

// ===========================================================================

static inline size_t align256(size_t x) { return (x + 255) & ~(size_t)255; }

extern "C" void kernel_launch(void* const* d_in, const int* in_sizes, int n_in,
                              void* d_out, int out_size, void* d_ws, size_t ws_size,
                              hipStream_t stream) {
    const float* weight = (const float*)d_in[0];
    const float* cj     = (const float*)d_in[1];
    const float* ci     = (const float*)d_in[2];
    const int*   src    = (const int*)d_in[3];
    const int*   dst    = (const int*)d_in[4];
    float* out = (float*)d_out;

    const int N = in_sizes[1];             // cj is [N,1]
    const int E = in_sizes[3];

    const int NBIN  = (N + BINW - 1) >> BINSHIFT;
    const int NTILE = (E + TB - 1) / TB;

    // --- main-path workspace layout ---
    size_t o_feat = 0;                                            // N*FEAT bf16
    size_t o_pair = align256(o_feat + (size_t)N * FEAT * 2);      // NBIN*CAP u32
    size_t o_cur  = align256(o_pair + (size_t)NBIN * CAP * 4);    // NBIN int
    size_t o_ni   = align256(o_cur + (size_t)NBIN * 4);           // N int2
    size_t need_new = o_ni + (size_t)N * 8;

    // mean edges/bin must leave headroom: require E <= NBIN * CAP / 2
    if (ws_size >= need_new && NBIN <= MAXBIN && N <= (1 << 17) &&
        (long)E <= (long)NBIN * (CAP / 2)) {
        char* ws = (char*)d_ws;
        unsigned short* feat16 = (unsigned short*)(ws + o_feat);
        unsigned* pair  = (unsigned*)(ws + o_pair);
        int* binCursor  = (int*)(ws + o_cur);
        int2* nodeinfo  = (int2*)(ws + o_ni);

        const int NC  = N * (FEAT / 8);
        const int ipt = 2;
        const int GC  = (NC + BBS * ipt - 1) / (BBS * ipt);   // convert blocks

        hipMemsetAsync(binCursor, 0, (size_t)NBIN * 4, stream);
        build_kernel<<<NTILE + GC, BBS, 0, stream>>>(
            weight, cj, src, dst, feat16, pair, binCursor, N, E, NBIN, NTILE, ipt);
        fine_sort_kernel<<<NBIN, 1024, 0, stream>>>(pair, binCursor, nodeinfo, N);
        long threads = (long)N * 64;
        gather_kernel<<<(int)((threads + 255) / 256), 256, 0, stream>>>(
            feat16, ci, nodeinfo, (const int*)pair, out, N);
        return;
    }

    // --- mid tier: per-node CSR path ---
    const int NB = (N + 255) / 256;
    size_t m_off = 0;                                              // (N+1) int
    size_t m_cur = align256(m_off + (size_t)(N + 1) * 4);          // N int
    size_t m_bsm = align256(m_cur + (size_t)N * 4);                // 512 int
    size_t m_src = align256(m_bsm + 512 * 4);                      // E int
    size_t m_ft  = align256(m_src + (size_t)E * 4);                // N*FEAT bf16
    size_t need_mid = m_ft + (size_t)N * FEAT * 2;

    if (ws_size >= need_mid && NB <= 512) {
        char* ws = (char*)d_ws;
        int* offsets    = (int*)(ws + m_off);
        int* cursor     = (int*)(ws + m_cur);
        int* bsum       = (int*)(ws + m_bsm);
        int* src_sorted = (int*)(ws + m_src);
        unsigned short* feat16 = (unsigned short*)(ws + m_ft);

        zero_ints_kernel<<<NB, 256, 0, stream>>>(cursor, N);
        {
            long T = (long)N * (FEAT / 8);
            if ((long)E > T) T = E;
            convert_hist_kernel<<<(int)((T + 255) / 256), 256, 0, stream>>>(
                weight, cj, dst, cursor, feat16, N, E);
        }
        block_sum_kernel<<<NB, 256, 0, stream>>>(cursor, bsum, N);
        scan_bsum_kernel<<<1, 512, 0, stream>>>(bsum, NB);
        scan_counts_kernel<<<NB, 256, 0, stream>>>(cursor, bsum, offsets, cursor, N, E);
        bucket_kernel<<<(E + 255) / 256, 256, 0, stream>>>(src, dst, cursor, src_sorted, E);
        long threads = (long)N * 64;
        gather_mid_kernel<<<(int)((threads + 255) / 256), 256, 0, stream>>>(
            feat16, ci, offsets, src_sorted, out, N);
        return;
    }

    // --- last tier: atomics ---
    const int total = N * FEAT;
    const int n4 = total >> 2;
    gcmc_zero_kernel<<<(n4 + 255) / 256, 256, 0, stream>>>((float4*)out, n4);
    const long threads = (long)E * 32;
    gcmc_scatter_kernel<<<(int)((threads + 255) / 256), 256, 0, stream>>>(
        weight, cj, src, dst, out, E);
    gcmc_scale_kernel<<<(n4 + 255) / 256, 256, 0, stream>>>((float4*)out, ci, n4);
}